// Round 10
// baseline (229.763 us; speedup 1.0000x reference)
//
#include <hip/hip_runtime.h>
#include <hip/hip_bf16.h>

#define N_TOKENS 16384
#define DIM      2048
#define NEXP     64
#define TOPK     8
#define LOSCALE  2048.0f      // 2^11, exact power of two
#define NBLOCKS  512          // 32 tokens per block
#define TOKPB    32
#define LSTRIDE  66           // exchange stride: <=2-way bank aliasing
#define NREP     32           // replicated aux accumulators
#define KROUND   256          // k per staging round
#define NR       8            // rounds (K = 2048)
#define SROW     528          // stage row stride in halves (1056 B)

typedef _Float16 half8   __attribute__((ext_vector_type(8)));
typedef float    floatx4 __attribute__((ext_vector_type(4)));

// ---------------------------------------------------------------------------
// Kernel 0: split W (64x2048 fp32) into f16 hi/lo planes.
//   whi = (f16)w;  wlo = (f16)((w - (f32)whi) * 2^11)
// ---------------------------------------------------------------------------
__global__ __launch_bounds__(256) void wprep_kernel(const float* __restrict__ W,
                                                    _Float16* __restrict__ Whi,
                                                    _Float16* __restrict__ Wlo) {
    int i = blockIdx.x * 256 + threadIdx.x;
    float w = W[i];
    _Float16 h = (_Float16)w;
    Whi[i] = h;
    Wlo[i] = (_Float16)((w - (float)h) * LOSCALE);
}

// split 8 f32 -> f16 hi/lo half8 pair
__device__ __forceinline__ void split2x8(const float4& f0, const float4& f1,
                                         half8& H, half8& L) {
    float v[8] = {f0.x, f0.y, f0.z, f0.w, f1.x, f1.y, f1.z, f1.w};
    #pragma unroll
    for (int j = 0; j < 8; ++j) {
        _Float16 h = (_Float16)v[j];
        H[j] = h;
        L[j] = (_Float16)((v[j] - (float)h) * LOSCALE);
    }
}

// ---------------------------------------------------------------------------
// R10: R9's structure (the only one that improved: reg-staged LDS, one sync
// per round, expert-split MFMA waves, kernel-split aux) at MAX residency.
//
// R9 evidence: doubling waves/CU 8->16 gave 105->77.6us (the only big win in
// 9 rounds); occupancy 35%, all pipes still <20%, VGPR 52 (compiler sank the
// A-prefetch and it didn't matter -- TLP is the hiding mechanism, not
// intra-wave pipelining). This doubles residency again WITHOUT adding
// B-traffic: 1024-thread blocks (16 waves), still 32 tokens/block,
// 2 blocks/CU x 16 waves = 32 waves/CU = hardware cap (8/SIMD).
//   - waves = experts(4) x k-quarters(4): 64 k/round per wave; acc 16 VGPR,
//     bh[2]/bl[2] 16 VGPR -> total well under the 64-VGPR 8-waves/SIMD cap.
//   - stager: 1024 threads x 16B segments; slot analysis: writes (sr*66+ss)
//     mod 8 and reads (2*row16+quad+kq*8) mod 8 both uniform 8 lanes/slot
//     -> conflict-free both directions.
//   - one __syncthreads per round (counted-vmcnt variants all lost: R8).
//   - epilogue: xch (4 k-quarter planes) aliases stage[0]; 16 waves x 2
//     tokens; softmax + rank-select (lax.top_k semantics); NREP aux
//     replicas reduced by aux_kernel behind the kernel boundary.
// ---------------------------------------------------------------------------
__global__ __launch_bounds__(1024) void moe_kernel(const float* __restrict__ A,
                                                   const _Float16* __restrict__ Whi,
                                                   const _Float16* __restrict__ Wlo,
                                                   float* __restrict__ out_w,
                                                   float* __restrict__ out_i,
                                                   float* __restrict__ cnt_ws,
                                                   float* __restrict__ sp_ws) {
    __shared__ _Float16 stage[2][TOKPB][SROW];   // 67.6 KB (stage[0] reused as xch)
    __shared__ float    s_cnt[NEXP];
    __shared__ float    s_sp[NEXP];

    const int tid   = threadIdx.x;
    const int lane  = tid & 63;
    const int wv    = tid >> 6;      // 0..15
    const int es    = wv & 3;        // expert slab: experts [16es, 16es+16)
    const int kq    = wv >> 2;       // k quarter: [kq*64, kq*64+64) per round
    const int row16 = lane & 15;
    const int quad  = lane >> 4;
    const int tbase = blockIdx.x * TOKPB;

    if (tid < NEXP) { s_cnt[tid] = 0.f; s_sp[tid] = 0.f; }

    // ---- stager role: thread covers token row (tid>>5), 32B seg (tid&31) ----
    const int sr = tid >> 5;
    const int ss = tid & 31;
    const float* Ap = A + (size_t)(tbase + sr) * DIM + ss * 8;
    _Float16* swh0 = &stage[0][sr][0] + ss * 8;
    _Float16* swh1 = &stage[1][sr][0] + ss * 8;

    // ---- MFMA role: wave (es,kq) ----
    const _Float16* bhp = Whi + (size_t)(es * 16 + row16) * DIM + kq * 64 + quad * 8;
    const _Float16* blp = Wlo + (size_t)(es * 16 + row16) * DIM + kq * 64 + quad * 8;

    floatx4 acc0[2] = {};   // hi*hi         (mt = 0,1)
    floatx4 acc1[2] = {};   // hi*lo + lo*hi (carries 2^11)
    half8 bh[2], bl[2];

    // ---- prologue: stage round 0; preload B round 0 ----
    {
        float4 f0 = *(const float4*)(Ap);
        float4 f1 = *(const float4*)(Ap + 4);
        half8 h, l; split2x8(f0, f1, h, l);
        *(half8*)(swh0)       = h;
        *(half8*)(swh0 + 256) = l;
    }
    #pragma unroll
    for (int c = 0; c < 2; ++c) {
        bh[c] = *(const half8*)(bhp + c * 32);
        bl[c] = *(const half8*)(blp + c * 32);
    }
    __syncthreads();

    // ---- main loop: 8 rounds of 256 k ----
    for (int r = 0; r < NR; ++r) {
        float4 g0, g1;
        if (r < NR - 1) {                  // issue next round's A loads NOW
            const float* p = Ap + (r + 1) * KROUND;
            g0 = *(const float4*)(p);
            g1 = *(const float4*)(p + 4);
        }
        const _Float16* sb = &stage[r & 1][0][0];

        #pragma unroll
        for (int c = 0; c < 2; ++c) {
            const int k0 = kq * 64 + c * 32 + quad * 8;
            const _Float16* p0 = sb + row16 * SROW;
            const _Float16* p1 = sb + (16 + row16) * SROW;
            half8 a0h = *(const half8*)(p0 + k0);
            half8 a0l = *(const half8*)(p0 + 256 + k0);
            half8 a1h = *(const half8*)(p1 + k0);
            half8 a1l = *(const half8*)(p1 + 256 + k0);
            acc0[0] = __builtin_amdgcn_mfma_f32_16x16x32_f16(a0h, bh[c], acc0[0], 0, 0, 0);
            acc1[0] = __builtin_amdgcn_mfma_f32_16x16x32_f16(a0h, bl[c], acc1[0], 0, 0, 0);
            acc1[0] = __builtin_amdgcn_mfma_f32_16x16x32_f16(a0l, bh[c], acc1[0], 0, 0, 0);
            acc0[1] = __builtin_amdgcn_mfma_f32_16x16x32_f16(a1h, bh[c], acc0[1], 0, 0, 0);
            acc1[1] = __builtin_amdgcn_mfma_f32_16x16x32_f16(a1h, bl[c], acc1[1], 0, 0, 0);
            acc1[1] = __builtin_amdgcn_mfma_f32_16x16x32_f16(a1l, bh[c], acc1[1], 0, 0, 0);
            if (r < NR - 1) {              // in-place B reload for round r+1
                bh[c] = *(const half8*)(bhp + (r + 1) * KROUND + c * 32);
                bl[c] = *(const half8*)(blp + (r + 1) * KROUND + c * 32);
            }
        }

        if (r < NR - 1) {
            _Float16* swh = (r & 1) ? swh0 : swh1;
            half8 h, l; split2x8(g0, g1, h, l);
            *(half8*)(swh)       = h;
            *(half8*)(swh + 256) = l;
        }
        __syncthreads();
    }

    // ---- exchange (xch aliases stage[0]): [4 kq][32 tok][66] floats ----
    float* xch = (float*)&stage[0][0][0];
    const float inv = 1.0f / LOSCALE;
    #pragma unroll
    for (int mt = 0; mt < 2; ++mt)
        #pragma unroll
        for (int reg = 0; reg < 4; ++reg) {
            int tok = mt * 16 + quad * 4 + reg;
            xch[(kq * TOKPB + tok) * LSTRIDE + es * 16 + row16] =
                acc0[mt][reg] + acc1[mt][reg] * inv;
        }
    __syncthreads();

    // ---- epilogue: wave wv handles tokens [wv*2, wv*2+2); lane = expert ----
    float sp = 0.f, cnt = 0.f;
    for (int i = 0; i < 2; ++i) {
        int t = wv * 2 + i;
        float lg = (xch[t * LSTRIDE + lane]                + xch[(TOKPB + t) * LSTRIDE + lane])
                 + (xch[(2 * TOKPB + t) * LSTRIDE + lane]  + xch[(3 * TOKPB + t) * LSTRIDE + lane]);

        float m = lg;
        #pragma unroll
        for (int off = 32; off; off >>= 1) m = fmaxf(m, __shfl_xor(m, off));
        float e = expf(lg - m);
        float ssum = e;
        #pragma unroll
        for (int off = 32; off; off >>= 1) ssum += __shfl_xor(ssum, off);
        float score = e / ssum;
        sp += score;

        int rank = 0;
        #pragma unroll
        for (int j = 0; j < 64; ++j) {
            float sj = __shfl(score, j);
            rank += (sj > score) || (sj == score && j < lane);
        }
        bool sel = rank < TOPK;

        float v = sel ? score : 0.f;
        #pragma unroll
        for (int off = 32; off; off >>= 1) v += __shfl_xor(v, off);

        if (sel) {
            out_w[(size_t)(tbase + t) * TOPK + rank] = score / v;
            out_i[(size_t)(tbase + t) * TOPK + rank] = (float)lane;
            cnt += 1.f;
        }
    }

    atomicAdd(&s_sp[lane], sp);
    atomicAdd(&s_cnt[lane], cnt);
    __syncthreads();
    const int rep = (blockIdx.x & (NREP - 1)) * NEXP;
    if (tid < 64)       atomicAdd(&cnt_ws[rep + tid], s_cnt[tid]);
    else if (tid < 128) atomicAdd(&sp_ws[rep + tid - 64], s_sp[tid - 64]);
    // no fence/ticket: aux_kernel after the kernel boundary reduces replicas
}

// ---------------------------------------------------------------------------
// Kernel 2: reduce NREP replicas -> aux loss (kernel boundary = visibility).
// ---------------------------------------------------------------------------
__global__ __launch_bounds__(64) void aux_kernel(const float* __restrict__ cnt_ws,
                                                 const float* __restrict__ sp_ws,
                                                 float* __restrict__ out_aux) {
    int tid = threadIdx.x;
    float c = 0.f, p = 0.f;
    #pragma unroll
    for (int r = 0; r < NREP; ++r) {
        c += cnt_ws[r * NEXP + tid];
        p += sp_ws[r * NEXP + tid];
    }
    float v = (c / (float)(N_TOKENS * TOPK)) * (p / (float)N_TOKENS);
    #pragma unroll
    for (int off = 32; off; off >>= 1) v += __shfl_xor(v, off);
    if (tid == 0) out_aux[0] = 0.001f * (float)NEXP * v;
}

extern "C" void kernel_launch(void* const* d_in, const int* in_sizes, int n_in,
                              void* d_out, int out_size, void* d_ws, size_t ws_size,
                              hipStream_t stream) {
    const float* A = (const float*)d_in[0];   // hidden_states (16384 x 2048)
    const float* W = (const float*)d_in[1];   // weight        (64 x 2048)
    float* out = (float*)d_out;

    _Float16* whi    = (_Float16*)d_ws;
    _Float16* wlo    = whi + (size_t)NEXP * DIM;
    float*    cnt_ws = (float*)(wlo + (size_t)NEXP * DIM);
    float*    sp_ws  = cnt_ws + (size_t)NREP * NEXP;

    // zero cnt(8KB) + sp(8KB)
    hipMemsetAsync(cnt_ws, 0, 2 * NREP * NEXP * sizeof(float), stream);

    hipLaunchKernelGGL(wprep_kernel, dim3(NEXP * DIM / 256), dim3(256), 0, stream,
                       W, whi, wlo);

    float* out_w = out;
    float* out_i = out + (size_t)N_TOKENS * TOPK;
    float* out_a = out + 2 * (size_t)N_TOKENS * TOPK;

    hipLaunchKernelGGL(moe_kernel, dim3(NBLOCKS), dim3(1024), 0, stream,
                       A, whi, wlo, out_w, out_i, cnt_ws, sp_ws);

    hipLaunchKernelGGL(aux_kernel, dim3(1), dim3(64), 0, stream,
                       cnt_ws, sp_ws, out_a);
}

// Round 11
// 222.270 us; speedup vs baseline: 1.0337x; 1.0337x over previous
//
#include <hip/hip_runtime.h>
#include <hip/hip_bf16.h>

#define N_TOKENS 16384
#define DIM      2048
#define NEXP     64
#define TOPK     8
#define LOSCALE  2048.0f      // 2^11, exact power of two
#define NBLOCKS  512          // 32 tokens per block
#define TOKPB    32
#define LSTRIDE  66           // exchange stride: <=2-way bank aliasing
#define NREP     32           // replicated aux accumulators
#define KROUND   128          // k per staging round (shrunk: 4 blocks/CU)
#define NR       16           // rounds (K = 2048)
#define SROW     264          // stage row stride in halves = 33 16B-slots
                              // == 1 mod 8 -> reads AND writes permute slot
                              // residues within every aligned 8-lane group
                              // = conflict-free both directions

typedef _Float16 half8   __attribute__((ext_vector_type(8)));
typedef float    floatx4 __attribute__((ext_vector_type(4)));

// ---------------------------------------------------------------------------
// Kernel 0: split W (64x2048 fp32) into f16 hi/lo planes.
//   whi = (f16)w;  wlo = (f16)((w - (f32)whi) * 2^11)
// ---------------------------------------------------------------------------
__global__ __launch_bounds__(256) void wprep_kernel(const float* __restrict__ W,
                                                    _Float16* __restrict__ Whi,
                                                    _Float16* __restrict__ Wlo) {
    int i = blockIdx.x * 256 + threadIdx.x;
    float w = W[i];
    _Float16 h = (_Float16)w;
    Whi[i] = h;
    Wlo[i] = (_Float16)((w - (float)h) * LOSCALE);
}

// split 8 f32 -> f16 hi/lo half8 pair
__device__ __forceinline__ void split2x8(const float4& f0, const float4& f1,
                                         half8& H, half8& L) {
    float v[8] = {f0.x, f0.y, f0.z, f0.w, f1.x, f1.y, f1.z, f1.w};
    #pragma unroll
    for (int j = 0; j < 8; ++j) {
        _Float16 h = (_Float16)v[j];
        H[j] = h;
        L[j] = (_Float16)((v[j] - (float)h) * LOSCALE);
    }
}

// ---------------------------------------------------------------------------
// R11: R9's skeleton (the proven winner: 8-wave blocks, reg-staged LDS, one
// sync per round, expert-split MFMA waves, kernel-split aux) at 4 blocks/CU.
//
// Evidence: R9 (8w blocks, 2 blocks/CU) = 77.6us beat R10 (16w blocks,
// ~1.7 blocks/CU, same waves/CU) = 88us. Adding waves to the SAME barrier
// domain doesn't help (skew grows, work/barrier shrinks); waves in
// INDEPENDENT blocks fill each other's stage/barrier stalls. So: shrink
// LDS (KROUND 256->128, stage 33.8 KB) -> 4 blocks/CU x 8 waves =
// 32 waves/CU in 4 independent barrier domains. VGPR must stay <=64
// (R9/R10: 52/56).
//   - waves = experts(4) x k-halves(2): 64 k/round/wave, acc 16 VGPR,
//     bh[2]/bl[2].
//   - stager: 512 threads x 8 floats (32B) per round; SROW=264 -> writes
//     and ds_read_b128 reads both slot-permute per 8-lane group (free).
//   - one __syncthreads per round (R5/R8: counted-vmcnt variants lost).
//   - epilogue: xch (2 k-half planes) aliases stage; softmax + rank-select
//     (lax.top_k semantics); NREP aux replicas; aux_kernel finalizes.
// ---------------------------------------------------------------------------
__global__ __launch_bounds__(512) void moe_kernel(const float* __restrict__ A,
                                                  const _Float16* __restrict__ Whi,
                                                  const _Float16* __restrict__ Wlo,
                                                  float* __restrict__ out_w,
                                                  float* __restrict__ out_i,
                                                  float* __restrict__ cnt_ws,
                                                  float* __restrict__ sp_ws) {
    __shared__ _Float16 stage[2][TOKPB][SROW];   // 33.8 KB (stage[0] reused as xch)
    __shared__ float    s_cnt[NEXP];
    __shared__ float    s_sp[NEXP];

    const int tid   = threadIdx.x;
    const int lane  = tid & 63;
    const int wv    = tid >> 6;      // 0..7
    const int es    = wv & 3;        // expert slab: experts [16es, 16es+16)
    const int kh    = wv >> 2;       // k half of the round: [kh*64, kh*64+64)
    const int row16 = lane & 15;
    const int quad  = lane >> 4;
    const int tbase = blockIdx.x * TOKPB;

    if (tid < NEXP) { s_cnt[tid] = 0.f; s_sp[tid] = 0.f; }

    // ---- stager role: thread covers token row (tid>>4), 32B seg (tid&15) ----
    const int sr = tid >> 4;
    const int ss = tid & 15;
    const float* Ap = A + (size_t)(tbase + sr) * DIM + ss * 8;
    _Float16* swh0 = &stage[0][sr][0] + ss * 8;
    _Float16* swh1 = &stage[1][sr][0] + ss * 8;

    // ---- MFMA role: wave (es, kh) ----
    const _Float16* bhp = Whi + (size_t)(es * 16 + row16) * DIM + kh * 64 + quad * 8;
    const _Float16* blp = Wlo + (size_t)(es * 16 + row16) * DIM + kh * 64 + quad * 8;

    floatx4 acc0[2] = {};   // hi*hi         (mt = 0,1)
    floatx4 acc1[2] = {};   // hi*lo + lo*hi (carries 2^11)
    half8 bh[2], bl[2];

    // ---- prologue: stage round 0; preload B round 0 ----
    {
        float4 f0 = *(const float4*)(Ap);
        float4 f1 = *(const float4*)(Ap + 4);
        half8 h, l; split2x8(f0, f1, h, l);
        *(half8*)(swh0)       = h;    // hi plane: [0,128)
        *(half8*)(swh0 + 128) = l;    // lo plane: [128,256)
    }
    #pragma unroll
    for (int c = 0; c < 2; ++c) {
        bh[c] = *(const half8*)(bhp + c * 32);
        bl[c] = *(const half8*)(blp + c * 32);
    }
    __syncthreads();

    // ---- main loop: 16 rounds of 128 k ----
    for (int r = 0; r < NR; ++r) {
        float4 g0, g1;
        if (r < NR - 1) {                  // issue next round's A loads NOW
            const float* p = Ap + (r + 1) * KROUND;
            g0 = *(const float4*)(p);
            g1 = *(const float4*)(p + 4);
        }
        const _Float16* sb = &stage[r & 1][0][0];

        #pragma unroll
        for (int c = 0; c < 2; ++c) {
            const int k0 = kh * 64 + c * 32 + quad * 8;
            const _Float16* p0 = sb + row16 * SROW;
            const _Float16* p1 = sb + (16 + row16) * SROW;
            half8 a0h = *(const half8*)(p0 + k0);
            half8 a0l = *(const half8*)(p0 + 128 + k0);
            half8 a1h = *(const half8*)(p1 + k0);
            half8 a1l = *(const half8*)(p1 + 128 + k0);
            acc0[0] = __builtin_amdgcn_mfma_f32_16x16x32_f16(a0h, bh[c], acc0[0], 0, 0, 0);
            acc1[0] = __builtin_amdgcn_mfma_f32_16x16x32_f16(a0h, bl[c], acc1[0], 0, 0, 0);
            acc1[0] = __builtin_amdgcn_mfma_f32_16x16x32_f16(a0l, bh[c], acc1[0], 0, 0, 0);
            acc0[1] = __builtin_amdgcn_mfma_f32_16x16x32_f16(a1h, bh[c], acc0[1], 0, 0, 0);
            acc1[1] = __builtin_amdgcn_mfma_f32_16x16x32_f16(a1h, bl[c], acc1[1], 0, 0, 0);
            acc1[1] = __builtin_amdgcn_mfma_f32_16x16x32_f16(a1l, bh[c], acc1[1], 0, 0, 0);
            if (r < NR - 1) {              // in-place B reload for round r+1
                bh[c] = *(const half8*)(bhp + (r + 1) * KROUND + c * 32);
                bl[c] = *(const half8*)(blp + (r + 1) * KROUND + c * 32);
            }
        }

        if (r < NR - 1) {
            _Float16* swh = (r & 1) ? swh0 : swh1;
            half8 h, l; split2x8(g0, g1, h, l);
            *(half8*)(swh)       = h;
            *(half8*)(swh + 128) = l;
        }
        __syncthreads();
    }

    // ---- exchange (xch aliases stage): [2 khalf][32 tok][66] floats ----
    float* xch = (float*)&stage[0][0][0];
    const float inv = 1.0f / LOSCALE;
    #pragma unroll
    for (int mt = 0; mt < 2; ++mt)
        #pragma unroll
        for (int reg = 0; reg < 4; ++reg) {
            int tok = mt * 16 + quad * 4 + reg;
            xch[(kh * TOKPB + tok) * LSTRIDE + es * 16 + row16] =
                acc0[mt][reg] + acc1[mt][reg] * inv;
        }
    __syncthreads();

    // ---- epilogue: wave wv handles tokens [wv*4, wv*4+4); lane = expert ----
    float sp = 0.f, cnt = 0.f;
    for (int i = 0; i < 4; ++i) {
        int t = wv * 4 + i;
        float lg = xch[t * LSTRIDE + lane] + xch[(TOKPB + t) * LSTRIDE + lane];

        float m = lg;
        #pragma unroll
        for (int off = 32; off; off >>= 1) m = fmaxf(m, __shfl_xor(m, off));
        float e = expf(lg - m);
        float ssum = e;
        #pragma unroll
        for (int off = 32; off; off >>= 1) ssum += __shfl_xor(ssum, off);
        float score = e / ssum;
        sp += score;

        int rank = 0;
        #pragma unroll
        for (int j = 0; j < 64; ++j) {
            float sj = __shfl(score, j);
            rank += (sj > score) || (sj == score && j < lane);
        }
        bool sel = rank < TOPK;

        float v = sel ? score : 0.f;
        #pragma unroll
        for (int off = 32; off; off >>= 1) v += __shfl_xor(v, off);

        if (sel) {
            out_w[(size_t)(tbase + t) * TOPK + rank] = score / v;
            out_i[(size_t)(tbase + t) * TOPK + rank] = (float)lane;
            cnt += 1.f;
        }
    }

    atomicAdd(&s_sp[lane], sp);
    atomicAdd(&s_cnt[lane], cnt);
    __syncthreads();
    const int rep = (blockIdx.x & (NREP - 1)) * NEXP;
    if (tid < 64)       atomicAdd(&cnt_ws[rep + tid], s_cnt[tid]);
    else if (tid < 128) atomicAdd(&sp_ws[rep + tid - 64], s_sp[tid - 64]);
    // no fence/ticket: aux_kernel after the kernel boundary reduces replicas
}

// ---------------------------------------------------------------------------
// Kernel 2: reduce NREP replicas -> aux loss (kernel boundary = visibility).
// ---------------------------------------------------------------------------
__global__ __launch_bounds__(64) void aux_kernel(const float* __restrict__ cnt_ws,
                                                 const float* __restrict__ sp_ws,
                                                 float* __restrict__ out_aux) {
    int tid = threadIdx.x;
    float c = 0.f, p = 0.f;
    #pragma unroll
    for (int r = 0; r < NREP; ++r) {
        c += cnt_ws[r * NEXP + tid];
        p += sp_ws[r * NEXP + tid];
    }
    float v = (c / (float)(N_TOKENS * TOPK)) * (p / (float)N_TOKENS);
    #pragma unroll
    for (int off = 32; off; off >>= 1) v += __shfl_xor(v, off);
    if (tid == 0) out_aux[0] = 0.001f * (float)NEXP * v;
}

extern "C" void kernel_launch(void* const* d_in, const int* in_sizes, int n_in,
                              void* d_out, int out_size, void* d_ws, size_t ws_size,
                              hipStream_t stream) {
    const float* A = (const float*)d_in[0];   // hidden_states (16384 x 2048)
    const float* W = (const float*)d_in[1];   // weight        (64 x 2048)
    float* out = (float*)d_out;

    _Float16* whi    = (_Float16*)d_ws;
    _Float16* wlo    = whi + (size_t)NEXP * DIM;
    float*    cnt_ws = (float*)(wlo + (size_t)NEXP * DIM);
    float*    sp_ws  = cnt_ws + (size_t)NREP * NEXP;

    // zero cnt(8KB) + sp(8KB)
    hipMemsetAsync(cnt_ws, 0, 2 * NREP * NEXP * sizeof(float), stream);

    hipLaunchKernelGGL(wprep_kernel, dim3(NEXP * DIM / 256), dim3(256), 0, stream,
                       W, whi, wlo);

    float* out_w = out;
    float* out_i = out + (size_t)N_TOKENS * TOPK;
    float* out_a = out + 2 * (size_t)N_TOKENS * TOPK;

    hipLaunchKernelGGL(moe_kernel, dim3(NBLOCKS), dim3(512), 0, stream,
                       A, whi, wlo, out_w, out_i, cnt_ws, sp_ws);

    hipLaunchKernelGGL(aux_kernel, dim3(1), dim3(64), 0, stream,
                       cnt_ws, sp_ws, out_a);
}